// Round 10
// baseline (492.416 us; speedup 1.0000x reference)
//
#include <hip/hip_runtime.h>
#include <hip/hip_bf16.h>
#include <math.h>

// CGConv: N=100000 atoms, M=12 nbrs, F=64 atom-feat, B=41 bond-feat
// gated = [self | nbr | bond] @ W + b ; BN1 over N*M rows ;
// summed = sum_j sigmoid(filter)*softplus(core) ; BN2 over N rows ;
// out = softplus(atom + summed_bn)
//
// R10: hybrid of R7 + R9 (efficiency-per-byte, not bytes, decides).
//  - k_gemm2: bond-only K=64 MFMA (contiguous staging, zero gather in
//    stage), Pself/Pnbr added in epilogue (the ONE scattered gather),
//    BN1 stats accumulated, gated stored bf16 in fragment layout.
//  - k_apply: R7-style pure stream of gated (runs at ~85% BW, measured),
//    gate + Y-transpose + nbr-sum + BN2 partials.
//  - occupancy: single-buffer LDS (6.9KB) + launch_bounds(256,6) -> 6
//    blocks/CU (R9 was 5 at 54%); apply at (256,8).
// BN1 two-pass is forced (sumsq cross-term Sum v_r*w_ij is per-pair);
// bias b cancels through BN1 (shift invariance).

#define NATOMS  100000
#define MNBR    12
#define FDIM    64
#define BDIM    41
#define C2F     128
#define EPSBN   1e-5f
#define NBLK    2048              // pair-kernel grid (= #partial slots)
#define GROUPS  (NATOMS/4)        // 25000 groups of 4 atoms = 48 pairs
#define AR      72                // pair A-tile row stride (shorts), K=64+pad
#define PR      72                // proj A-tile row stride (shorts)

typedef __attribute__((ext_vector_type(8))) short  short8;   // bf16 x8 frag
typedef __attribute__((ext_vector_type(4))) float  f32x4;    // C/D frag

__device__ __forceinline__ float softplusf(float x) {
    return fmaxf(x, 0.f) + __logf(1.f + __expf(-fabsf(x)));
}
__device__ __forceinline__ float sigmoidf(float x) {
    return 1.f / (1.f + __expf(-x));
}
__device__ __forceinline__ unsigned short f2bf(float f) {
    unsigned int x = __builtin_bit_cast(unsigned int, f);
    unsigned int r = (x + 0x7fff + ((x >> 16) & 1)) >> 16;  // RNE
    return (unsigned short)r;
}
__device__ __forceinline__ unsigned int pkbf(float a, float b) {
    unsigned short lo = __builtin_bit_cast(unsigned short, __float2bfloat16(a));
    unsigned short hi = __builtin_bit_cast(unsigned short, __float2bfloat16(b));
    return (unsigned)lo | ((unsigned)hi << 16);
}
__device__ __forceinline__ float bflo(unsigned int u) {
    return __builtin_bit_cast(float, u << 16);
}
__device__ __forceinline__ float bfhi(unsigned int u) {
    return __builtin_bit_cast(float, u & 0xffff0000u);
}
__device__ __forceinline__ float bf2f(unsigned short u) {
    return __builtin_bit_cast(float, ((unsigned int)u) << 16);
}

// ---------------- kernel 0: prepack W fragments ----------------
// Wal[h<2][n<8][ks<2][lane][e]: row = h*64+ks*32+(lane>>4)*8+e, col = n*16+(lane&15)
// Wbd[n<8][ks<2][lane][e]:      kk  = ks*32+(lane>>4)*8+e; kk<41 -> W[128+kk][col] else 0
__global__ __launch_bounds__(256) void k_pack(
    const float* __restrict__ W,
    unsigned short* __restrict__ Wal, unsigned short* __restrict__ Wbd)
{
    const int t0 = blockIdx.x*256 + threadIdx.x;
    for (int idx = t0; idx < 2*8*2*64*8; idx += gridDim.x*256) {
        int e = idx & 7, lane = (idx >> 3) & 63, ks = (idx >> 9) & 1;
        int n = (idx >> 10) & 7, h = idx >> 13;
        int k   = h*64 + ks*32 + (lane >> 4)*8 + e;
        int col = n*16 + (lane & 15);
        Wal[idx] = f2bf(W[k*C2F + col]);
    }
    for (int idx = t0; idx < 8*2*64*8; idx += gridDim.x*256) {
        int e = idx & 7, lane = (idx >> 3) & 63, ks = (idx >> 9) & 1, n = idx >> 10;
        int kk  = ks*32 + (lane >> 4)*8 + e;
        int col = n*16 + (lane & 15);
        float v = (kk < BDIM) ? W[(2*FDIM + kk)*C2F + col] : 0.f;
        Wbd[idx] = f2bf(v);
    }
}

// ---------------- kernel 1: Pself & Pnbr = atom @ {W_self, W_nbr} ----------------
__global__ __launch_bounds__(256, 4) void k_proj(
    const float* __restrict__ atomF, const unsigned short* __restrict__ Wal,
    unsigned short* __restrict__ PselfBf, unsigned short* __restrict__ PnbrBf)
{
    __shared__ __align__(16) unsigned short A[64*PR];
    const int tid = threadIdx.x, w = tid >> 6, lane = tid & 63;
    const int g = lane >> 4, x = lane & 15;
    short8 Bs0[2], Bs1[2], Bn0[2], Bn1[2];
    #pragma unroll
    for (int ks = 0; ks < 2; ++ks) {
        Bs0[ks] = *(const short8*)(Wal + (((0*8 + w    )*2 + ks)*64 + lane)*8);
        Bs1[ks] = *(const short8*)(Wal + (((0*8 + w + 4)*2 + ks)*64 + lane)*8);
        Bn0[ks] = *(const short8*)(Wal + (((1*8 + w    )*2 + ks)*64 + lane)*8);
        Bn1[ks] = *(const short8*)(Wal + (((1*8 + w + 4)*2 + ks)*64 + lane)*8);
    }
    for (int a0 = blockIdx.x*64; a0 < NATOMS; a0 += gridDim.x*64) {
        __syncthreads();
        #pragma unroll
        for (int it = 0; it < 4; ++it) {
            int idx = it*256 + tid;
            int p = idx >> 4, c = idx & 15;
            int i = a0 + p;
            float4 v = make_float4(0.f, 0.f, 0.f, 0.f);
            if (i < NATOMS) v = *(const float4*)(atomF + (size_t)i*FDIM + 4*c);
            uint2 u; u.x = pkbf(v.x, v.y); u.y = pkbf(v.z, v.w);
            *(uint2*)(A + p*PR + 4*c) = u;
        }
        __syncthreads();
        f32x4 z = {0.f, 0.f, 0.f, 0.f};
        f32x4 acc[4][4];
        #pragma unroll
        for (int m = 0; m < 4; ++m)
            { acc[m][0] = z; acc[m][1] = z; acc[m][2] = z; acc[m][3] = z; }
        #pragma unroll
        for (int ks = 0; ks < 2; ++ks) {
            #pragma unroll
            for (int m = 0; m < 4; ++m) {
                short8 a = *(const short8*)(A + (m*16 + x)*PR + ks*32 + g*8);
                acc[m][0] = __builtin_amdgcn_mfma_f32_16x16x32_bf16(a, Bs0[ks], acc[m][0], 0, 0, 0);
                acc[m][1] = __builtin_amdgcn_mfma_f32_16x16x32_bf16(a, Bs1[ks], acc[m][1], 0, 0, 0);
                acc[m][2] = __builtin_amdgcn_mfma_f32_16x16x32_bf16(a, Bn0[ks], acc[m][2], 0, 0, 0);
                acc[m][3] = __builtin_amdgcn_mfma_f32_16x16x32_bf16(a, Bn1[ks], acc[m][3], 0, 0, 0);
            }
        }
        #pragma unroll
        for (int m = 0; m < 4; ++m) {
            int i = a0 + m*16 + g*4;
            #pragma unroll
            for (int rg = 0; rg < 4; ++rg) {
                if (i + rg < NATOMS) {
                    size_t o = (size_t)(i+rg)*C2F;
                    PselfBf[o + w*16 + x]       = f2bf(acc[m][0][rg]);
                    PselfBf[o + (w+4)*16 + x]   = f2bf(acc[m][1][rg]);
                    PnbrBf [o + w*16 + x]       = f2bf(acc[m][2][rg]);
                    PnbrBf [o + (w+4)*16 + x]   = f2bf(acc[m][3][rg]);
                }
            }
        }
    }
}

// ---------------- kernel 2: bond GEMM + P adds + BN1 stats + gated store ----------------
// A rows = bond(41)|pad bf16, K=64 (2 ksteps), M=48 pairs; bond block of a
// group is contiguous (7.8KB). Wave w owns n-tiles {w, w+4}: channels
// ch0 = w*16+x (filter) and ch0+64 (core) in the same lane.
// gated layout: uint4 index = ((grp*4 + w)*3 + m)*64 + lane.
__global__ __launch_bounds__(256, 6) void k_gemm2(
    const int* __restrict__ nbr, const float* __restrict__ bond,
    const unsigned short* __restrict__ Wbd,
    const unsigned short* __restrict__ PselfBf,
    const unsigned short* __restrict__ PnbrBf,
    uint4* __restrict__ gated, float* __restrict__ partial1)
{
    __shared__ __align__(16) unsigned short A[48*AR];
    const int tid = threadIdx.x, w = tid >> 6, lane = tid & 63;
    const int g = lane >> 4, x = lane & 15;
    const int ch0 = w*16 + x;
    short8 B0[2], B1[2];
    #pragma unroll
    for (int ks = 0; ks < 2; ++ks) {
        B0[ks] = *(const short8*)(Wbd + ((w*2 + ks)*64 + lane)*8);
        B1[ks] = *(const short8*)(Wbd + (((w+4)*2 + ks)*64 + lane)*8);
    }
    for (int idx = tid; idx < 48*AR/2; idx += 256) ((unsigned int*)A)[idx] = 0u;
    float s0 = 0.f, q0 = 0.f, s1 = 0.f, q1 = 0.f;

    for (int grp = blockIdx.x; grp < GROUPS; grp += gridDim.x) {
        const int base = grp*4;
        __syncthreads();                       // prior reads of A done
        // early loads for the epilogue (overlap stage+MFMA)
        int4 ridx[3];
        float ps0[3], ps1[3];
        #pragma unroll
        for (int m = 0; m < 3; ++m) {
            ridx[m] = *(const int4*)(nbr + base*MNBR + m*16 + g*4);
            int ia = base + (m*16 + g*4)/12;   // uniform over rg (proven)
            ps0[m] = bf2f(PselfBf[(size_t)ia*C2F + ch0]);
            ps1[m] = bf2f(PselfBf[(size_t)ia*C2F + 64 + ch0]);
        }
        // stage bond (contiguous block, no dependent chain)
        #pragma unroll
        for (int it = 0; it < 3; ++it) {
            int idx = it*256 + tid;
            int p = idx >> 4, c = idx & 15;
            if (c < 11) {
                const float* bp = bond + (size_t)base*(MNBR*BDIM) + p*BDIM + 4*c;
                float b0 = bp[0], b1 = 0.f, b2 = 0.f, b3 = 0.f;
                if (c < 10) { b1 = bp[1]; b2 = bp[2]; b3 = bp[3]; }
                uint2 u; u.x = pkbf(b0, b1); u.y = pkbf(b2, b3);
                *(uint2*)(&A[p*AR + 4*c]) = u;
            }
        }
        __syncthreads();
        f32x4 z = {0.f, 0.f, 0.f, 0.f};
        f32x4 acc[3][2];
        #pragma unroll
        for (int m = 0; m < 3; ++m) { acc[m][0] = z; acc[m][1] = z; }
        #pragma unroll
        for (int ks = 0; ks < 2; ++ks) {
            #pragma unroll
            for (int m = 0; m < 3; ++m) {
                short8 a = *(const short8*)(&A[(m*16 + x)*AR + ks*32 + g*8]);
                acc[m][0] = __builtin_amdgcn_mfma_f32_16x16x32_bf16(a, B0[ks], acc[m][0], 0, 0, 0);
                acc[m][1] = __builtin_amdgcn_mfma_f32_16x16x32_bf16(a, B1[ks], acc[m][1], 0, 0, 0);
            }
        }
        uint4* gbase = gated + ((size_t)grp*4 + w)*3*64 + lane;
        #pragma unroll
        for (int m = 0; m < 3; ++m) {
            const int rr[4] = {ridx[m].x, ridx[m].y, ridx[m].z, ridx[m].w};
            float v0[4], v1[4];
            #pragma unroll
            for (int rg = 0; rg < 4; ++rg) {
                size_t o = (size_t)rr[rg]*C2F;
                v0[rg] = acc[m][0][rg] + ps0[m] + bf2f(PnbrBf[o + ch0]);
                v1[rg] = acc[m][1][rg] + ps1[m] + bf2f(PnbrBf[o + 64 + ch0]);
                s0 += v0[rg]; q0 = fmaf(v0[rg], v0[rg], q0);
                s1 += v1[rg]; q1 = fmaf(v1[rg], v1[rg], q1);
            }
            uint4 pk;
            pk.x = pkbf(v0[0], v0[1]); pk.y = pkbf(v0[2], v0[3]);
            pk.z = pkbf(v1[0], v1[1]); pk.w = pkbf(v1[2], v1[3]);
            gbase[m*64] = pk;
        }
    }
    s0 += __shfl_xor(s0, 16); s0 += __shfl_xor(s0, 32);
    s1 += __shfl_xor(s1, 16); s1 += __shfl_xor(s1, 32);
    q0 += __shfl_xor(q0, 16); q0 += __shfl_xor(q0, 32);
    q1 += __shfl_xor(q1, 16); q1 += __shfl_xor(q1, 32);
    if (g == 0) {
        float* pb = partial1 + blockIdx.x*256;     // {sum[128], sumsq[128]}
        pb[ch0]            = s0; pb[64 + ch0]        = s1;
        pb[C2F + ch0]      = q0; pb[C2F + 64 + ch0]  = q1;
    }
}

// ---------------- kernel: partial reduce NBLK -> 128 slots ----------------
__global__ __launch_bounds__(256) void k_red(
    const float* __restrict__ in, float* __restrict__ outp, int width)
{
    const int b = blockIdx.x;
    for (int c = threadIdx.x; c < width; c += 256) {
        float s = 0.f;
        #pragma unroll
        for (int k = 0; k < NBLK/128; ++k) s += in[(size_t)(b*(NBLK/128) + k)*width + c];
        outp[(size_t)b*width + c] = s;
    }
}

// ---------------- kernel 3: finalize BN1 params ----------------
__global__ __launch_bounds__(1024) void k_bn1_finalize(
    const float* __restrict__ red1, const float* __restrict__ scale,
    const float* __restrict__ offset, float* __restrict__ prm1)
{
    __shared__ float redS[1024], redQ[1024];
    const int tid = threadIdx.x, c = tid & 127, h = tid >> 7;   // 8 slices
    float S = 0.f, Q = 0.f;
    for (int blk = h; blk < 128; blk += 8) {
        S += red1[blk*256 + c];
        Q += red1[blk*256 + 128 + c];
    }
    redS[tid] = S; redQ[tid] = Q;
    __syncthreads();
    if (tid < 128) {
        float Sa = 0.f, Qa = 0.f;
        #pragma unroll
        for (int hh = 0; hh < 8; ++hh) { Sa += redS[hh*128 + c]; Qa += redQ[hh*128 + c]; }
        const float invn = 1.f / (float)(NATOMS * MNBR);
        float mean = Sa * invn;
        float var  = Qa * invn - mean*mean;
        float inv  = scale[c] * rsqrtf(var + EPSBN);
        prm1[c]       = inv;
        prm1[128 + c] = offset[c] - mean*inv;       // folded offset
    }
}

// ---------------- kernel 4: apply pass (stream gated, gate, nbr-sum) ----------------
__global__ __launch_bounds__(256, 8) void k_apply(
    const uint4* __restrict__ gated, const float* __restrict__ prm1,
    float* __restrict__ summed, float* __restrict__ partial2)
{
    __shared__ float Y[12*66];
    __shared__ float red[256];
    const int tid = threadIdx.x, w = tid >> 6, lane = tid & 63;
    const int g = lane >> 4, x = lane & 15;
    const int ch0 = w*16 + x;
    const float iv0 = prm1[ch0],      of0 = prm1[C2F + ch0];
    const float iv1 = prm1[64 + ch0], of1 = prm1[C2F + 64 + ch0];
    float s2 = 0.f, q2 = 0.f;

    for (int grp = blockIdx.x; grp < GROUPS; grp += gridDim.x) {
        __syncthreads();                       // Y reuse
        const uint4* gbase = gated + ((size_t)grp*4 + w)*3*64 + lane;
        #pragma unroll
        for (int m = 0; m < 3; ++m) {
            uint4 pk = gbase[m*64];
            float y00 = bflo(pk.x)*iv0 + of0, y01 = bfhi(pk.x)*iv0 + of0;
            float y02 = bflo(pk.y)*iv0 + of0, y03 = bfhi(pk.y)*iv0 + of0;
            float y10 = bflo(pk.z)*iv1 + of1, y11 = bfhi(pk.z)*iv1 + of1;
            float y12 = bflo(pk.w)*iv1 + of1, y13 = bfhi(pk.w)*iv1 + of1;
            float sY = sigmoidf(y00)*softplusf(y10) + sigmoidf(y01)*softplusf(y11)
                     + sigmoidf(y02)*softplusf(y12) + sigmoidf(y03)*softplusf(y13);
            Y[(m*4 + g)*66 + ch0] = sY;        // atom = (m*4+g)/3
        }
        __syncthreads();
        float sv = Y[(3*w)*66 + lane] + Y[(3*w + 1)*66 + lane] + Y[(3*w + 2)*66 + lane];
        summed[(size_t)(grp*4 + w)*FDIM + lane] = sv;
        s2 += sv; q2 = fmaf(sv, sv, q2);
    }
    red[tid] = s2; __syncthreads();
    if (tid < 64) partial2[blockIdx.x*128 + tid]
        = red[tid] + red[tid+64] + red[tid+128] + red[tid+192];
    __syncthreads();
    red[tid] = q2; __syncthreads();
    if (tid < 64) partial2[blockIdx.x*128 + 64 + tid]
        = red[tid] + red[tid+64] + red[tid+128] + red[tid+192];
}

// ---------------- kernel 5: finalize BN2 params ----------------
__global__ __launch_bounds__(1024) void k_bn2_finalize(
    const float* __restrict__ red2, const float* __restrict__ scale,
    const float* __restrict__ offset, float* __restrict__ prm2)
{
    __shared__ float redS[1024], redQ[1024];
    const int tid = threadIdx.x, f = tid & 63, h = tid >> 6;    // 16 slices
    float S = 0.f, Q = 0.f;
    for (int blk = h; blk < 128; blk += 16) {
        S += red2[blk*128 + f];
        Q += red2[blk*128 + 64 + f];
    }
    redS[tid] = S; redQ[tid] = Q;
    __syncthreads();
    if (tid < 64) {
        float Sa = 0.f, Qa = 0.f;
        #pragma unroll
        for (int hh = 0; hh < 16; ++hh) { Sa += redS[hh*64 + f]; Qa += redQ[hh*64 + f]; }
        const float invn = 1.f / (float)NATOMS;
        float mean = Sa * invn;
        float var  = Qa * invn - mean*mean;
        float inv  = scale[f] * rsqrtf(var + EPSBN);
        prm2[f]      = inv;
        prm2[64 + f] = offset[f] - mean*inv;
    }
}

// ---------------- kernel 6: residual + softplus ----------------
__global__ __launch_bounds__(256) void k_final(
    const float* __restrict__ atomF, const float* __restrict__ summed,
    const float* __restrict__ prm2, float* __restrict__ out)
{
    __shared__ float iv[64], of[64];
    if (threadIdx.x < 64) {
        iv[threadIdx.x] = prm2[threadIdx.x];
        of[threadIdx.x] = prm2[64 + threadIdx.x];
    }
    __syncthreads();
    const int total4 = NATOMS*FDIM/4;
    for (int t = blockIdx.x*blockDim.x + threadIdx.x; t < total4;
         t += gridDim.x*blockDim.x) {
        float4 a = ((const float4*)atomF)[t];
        float4 s = ((const float4*)summed)[t];
        int fb = (t*4) & 63;
        float4 r;
        r.x = softplusf(a.x + s.x*iv[fb]   + of[fb]);
        r.y = softplusf(a.y + s.y*iv[fb+1] + of[fb+1]);
        r.z = softplusf(a.z + s.z*iv[fb+2] + of[fb+2]);
        r.w = softplusf(a.w + s.w*iv[fb+3] + of[fb+3]);
        ((float4*)out)[t] = r;
    }
}

extern "C" void kernel_launch(void* const* d_in, const int* in_sizes, int n_in,
                              void* d_out, int out_size, void* d_ws, size_t ws_size,
                              hipStream_t stream)
{
    const int*   nbr   = (const int*)  d_in[0];
    const float* atomF = (const float*)d_in[1];
    const float* bond  = (const float*)d_in[2];
    const float* W     = (const float*)d_in[3];
    // d_in[4] = b: cancels through BN1 (shift invariance) -> unused
    const float* s1    = (const float*)d_in[5];
    const float* o1    = (const float*)d_in[6];
    const float* s2    = (const float*)d_in[7];
    const float* o2    = (const float*)d_in[8];
    float* out = (float*)d_out;

    // ws layout (~385 MB)
    uint4* gated        = (uint4*)d_ws;                          // GROUPS*12*64*16B = 307.2MB
    unsigned short* PselfBf = (unsigned short*)(gated + (size_t)GROUPS*12*64);  // N*128 bf16
    unsigned short* PnbrBf  = PselfBf + (size_t)NATOMS*C2F;      // N*128 bf16
    float* summed   = (float*)(PnbrBf + (size_t)NATOMS*C2F);     // N*64 f32
    float* partial1 = summed   + (size_t)NATOMS*FDIM;            // NBLK*256
    float* partial2 = partial1 + (size_t)NBLK*256;               // NBLK*128
    float* red1     = partial2 + (size_t)NBLK*128;               // 128*256
    float* red2     = red1     + 128*256;                        // 128*128
    float* prm1     = red2     + 128*128;                        // 256
    float* prm2     = prm1     + 256;                            // 128
    unsigned short* Wal = (unsigned short*)(prm2 + 128);         // 16384 shorts
    unsigned short* Wbd = Wal + 16384;                           // 8192 shorts

    hipLaunchKernelGGL(k_pack,         dim3(64),   dim3(256),  0, stream, W, Wal, Wbd);
    hipLaunchKernelGGL(k_proj,         dim3(1024), dim3(256),  0, stream,
                       atomF, Wal, PselfBf, PnbrBf);
    hipLaunchKernelGGL(k_gemm2,        dim3(NBLK), dim3(256),  0, stream,
                       nbr, bond, Wbd, PselfBf, PnbrBf, gated, partial1);
    hipLaunchKernelGGL(k_red,          dim3(128),  dim3(256),  0, stream, partial1, red1, 256);
    hipLaunchKernelGGL(k_bn1_finalize, dim3(1),    dim3(1024), 0, stream, red1, s1, o1, prm1);
    hipLaunchKernelGGL(k_apply,        dim3(NBLK), dim3(256),  0, stream,
                       gated, prm1, summed, partial2);
    hipLaunchKernelGGL(k_red,          dim3(128),  dim3(256),  0, stream, partial2, red2, 128);
    hipLaunchKernelGGL(k_bn2_finalize, dim3(1),    dim3(1024), 0, stream, red2, s2, o2, prm2);
    hipLaunchKernelGGL(k_final,        dim3(2048), dim3(256),  0, stream, atomF, summed, prm2, out);
}

// Round 11
// 372.492 us; speedup vs baseline: 1.3219x; 1.3219x over previous
//
#include <hip/hip_runtime.h>
#include <hip/hip_bf16.h>
#include <math.h>

// CGConv: N=100000 atoms, M=12 nbrs, F=64 atom-feat, B=41 bond-feat
// gated = [self | nbr | bond] @ W + b ; BN1 over N*M rows ;
// summed = sum_j sigmoid(filter)*softplus(core) ; BN2 over N rows ;
// out = softplus(atom + summed_bn)
//
// R11 = R8 (best, 394us) + 2-deep neighbor-index pipeline in k_gemm.
// R8 lesson: 1-deep prefetch couldn't hide the 2-level chain
// nbr->gather (gather for t+1 stalls on nbr return mid-iteration).
// Now: nbr indices for t+1 live in registers since iteration t-1, so
// the gather issues with zero dependent wait; nbr(t+2) loads in parallel.
// R10 lesson (3rd spill): never cap launch_bounds above 4 waves/EU with
// MFMA accumulators live -> stay at (256,4).
// Two-phase structure (stats then apply) is forced: BN1's sumsq cross-term
// is irreducibly per-pair. bias b cancels through BN1 (shift invariance).

#define NATOMS  100000
#define MNBR    12
#define FDIM    64
#define BDIM    41
#define C2F     128
#define EPSBN   1e-5f
#define NBLK    2048              // pair-kernel grid (= #partial slots)
#define GROUPS  (NATOMS/4)        // 25000 groups of 4 atoms = 48 pairs
#define AR      136               // pair A-tile row stride (shorts)
#define PR      72                // proj A-tile row stride (shorts)

typedef __attribute__((ext_vector_type(8))) short  short8;   // bf16 x8 frag
typedef __attribute__((ext_vector_type(4))) float  f32x4;    // C/D frag

__device__ __forceinline__ float softplusf(float x) {
    return fmaxf(x, 0.f) + __logf(1.f + __expf(-fabsf(x)));
}
__device__ __forceinline__ float sigmoidf(float x) {
    return 1.f / (1.f + __expf(-x));
}
__device__ __forceinline__ unsigned short f2bf(float f) {
    unsigned int x = __builtin_bit_cast(unsigned int, f);
    unsigned int r = (x + 0x7fff + ((x >> 16) & 1)) >> 16;  // RNE
    return (unsigned short)r;
}
__device__ __forceinline__ unsigned int pkbf(float a, float b) {
    unsigned short lo = __builtin_bit_cast(unsigned short, __float2bfloat16(a));
    unsigned short hi = __builtin_bit_cast(unsigned short, __float2bfloat16(b));
    return (unsigned)lo | ((unsigned)hi << 16);
}
__device__ __forceinline__ float bflo(unsigned int u) {
    return __builtin_bit_cast(float, u << 16);
}
__device__ __forceinline__ float bfhi(unsigned int u) {
    return __builtin_bit_cast(float, u & 0xffff0000u);
}
__device__ __forceinline__ float bf2f(unsigned short u) {
    return __builtin_bit_cast(float, ((unsigned int)u) << 16);
}

// ---------------- kernel 0: prepack W fragments ----------------
// Wsn: self rows,  [n<8][ks<2][lane][e], k = ks*32+(lane>>4)*8+e, col=n*16+(lane&15)
// Wpk: nbr+bond rows, [n<8][ks<4][lane][e]; k<105 -> W[64+k][col] else 0
__global__ __launch_bounds__(256) void k_pack(
    const float* __restrict__ W,
    unsigned short* __restrict__ Wsn, unsigned short* __restrict__ Wpk)
{
    const int t0 = blockIdx.x*256 + threadIdx.x;
    for (int idx = t0; idx < 8*2*64*8; idx += gridDim.x*256) {
        int e = idx & 7, lane = (idx >> 3) & 63, ks = (idx >> 9) & 1, n = idx >> 10;
        int k   = ks*32 + (lane >> 4)*8 + e;
        int col = n*16 + (lane & 15);
        Wsn[idx] = f2bf(W[k*C2F + col]);
    }
    for (int idx = t0; idx < 8*4*64*8; idx += gridDim.x*256) {
        int e = idx & 7, lane = (idx >> 3) & 63, ks = (idx >> 9) & 3, n = idx >> 11;
        int k   = ks*32 + (lane >> 4)*8 + e;
        int col = n*16 + (lane & 15);
        float v = (k < 105) ? W[(64 + k)*C2F + col] : 0.f;
        Wpk[idx] = f2bf(v);
    }
}

// ---------------- kernel 1: Pself (MFMA) + atomBf pack ----------------
__global__ __launch_bounds__(256, 4) void k_proj(
    const float* __restrict__ atomF, const unsigned short* __restrict__ Wsn,
    unsigned short* __restrict__ PselfBf, unsigned short* __restrict__ atomBf)
{
    __shared__ __align__(16) unsigned short A[64*PR];
    const int tid = threadIdx.x, w = tid >> 6, lane = tid & 63;
    const int g = lane >> 4, x = lane & 15;
    short8 B0[2], B1[2];
    #pragma unroll
    for (int ks = 0; ks < 2; ++ks) {
        B0[ks] = *(const short8*)(Wsn + ((w*2 + ks)*64 + lane)*8);
        B1[ks] = *(const short8*)(Wsn + (((w+4)*2 + ks)*64 + lane)*8);
    }
    for (int a0 = blockIdx.x*64; a0 < NATOMS; a0 += gridDim.x*64) {
        __syncthreads();
        #pragma unroll
        for (int it = 0; it < 4; ++it) {
            int idx = it*256 + tid;
            int p = idx >> 4, c = idx & 15;
            int i = a0 + p;
            float4 v = make_float4(0.f, 0.f, 0.f, 0.f);
            if (i < NATOMS) v = *(const float4*)(atomF + (size_t)i*FDIM + 4*c);
            uint2 u; u.x = pkbf(v.x, v.y); u.y = pkbf(v.z, v.w);
            *(uint2*)(A + p*PR + 4*c) = u;
            if (i < NATOMS) *(uint2*)(atomBf + (size_t)i*FDIM + 4*c) = u;
        }
        __syncthreads();
        f32x4 z = {0.f, 0.f, 0.f, 0.f};
        f32x4 acc[4][2];
        #pragma unroll
        for (int m = 0; m < 4; ++m) { acc[m][0] = z; acc[m][1] = z; }
        #pragma unroll
        for (int ks = 0; ks < 2; ++ks) {
            #pragma unroll
            for (int m = 0; m < 4; ++m) {
                short8 a = *(const short8*)(A + (m*16 + x)*PR + ks*32 + g*8);
                acc[m][0] = __builtin_amdgcn_mfma_f32_16x16x32_bf16(a, B0[ks], acc[m][0], 0, 0, 0);
                acc[m][1] = __builtin_amdgcn_mfma_f32_16x16x32_bf16(a, B1[ks], acc[m][1], 0, 0, 0);
            }
        }
        #pragma unroll
        for (int m = 0; m < 4; ++m) {
            int i = a0 + m*16 + g*4;
            #pragma unroll
            for (int rg = 0; rg < 4; ++rg) {
                if (i + rg < NATOMS) {
                    PselfBf[(size_t)(i+rg)*C2F + w*16 + x]     = f2bf(acc[m][0][rg]);
                    PselfBf[(size_t)(i+rg)*C2F + (w+4)*16 + x] = f2bf(acc[m][1][rg]);
                }
            }
        }
    }
}

// ---------------- kernel 2: pair GEMM + BN1 stats + gated store ----------------
// A rows = [nbr(64) | bond(41) | pad] bf16, K=128 (4 ksteps), M=48 pairs.
// 2-deep index pipeline: rN holds nbr indices for group t+1 (loaded at t-1);
// gather(t+1) issues at t with zero dependent wait; nbr(t+2) -> rM issues
// in parallel; LDS write after MFMA (T14). Slot map: idx=it*256+tid,
// p=idx>>5 (pair), c=idx&31; c<16: nbr quad; 16<=c<27: bond quad.
__global__ __launch_bounds__(256, 4) void k_gemm(
    const int* __restrict__ nbr, const unsigned short* __restrict__ atomBf,
    const float* __restrict__ bond, const unsigned short* __restrict__ Wpk,
    const unsigned short* __restrict__ PselfBf,
    uint4* __restrict__ gated, float* __restrict__ partial1)
{
    __shared__ __align__(16) unsigned short A[2][48*AR];
    const int tid = threadIdx.x, w = tid >> 6, lane = tid & 63;
    const int g = lane >> 4, x = lane & 15;
    const int ch0 = w*16 + x;
    short8 B0[4], B1[4];
    #pragma unroll
    for (int ks = 0; ks < 4; ++ks) {
        B0[ks] = *(const short8*)(Wpk + ((w*4 + ks)*64 + lane)*8);
        B1[ks] = *(const short8*)(Wpk + (((w+4)*4 + ks)*64 + lane)*8);
    }
    for (int idx = tid; idx < 2*48*AR/2; idx += 256) ((unsigned int*)A)[idx] = 0u;

    uint2 st[6];
    int rN[6] = {0,0,0,0,0,0};
    int rM[6] = {0,0,0,0,0,0};
    float s0 = 0.f, q0 = 0.f, s1 = 0.f, q1 = 0.f;

#define LOAD_NBR(GRP, R)                                                      \
    {   const int base_ = (GRP)*4;                                            \
        _Pragma("unroll")                                                     \
        for (int it = 0; it < 6; ++it) {                                      \
            int idx = it*256 + tid;                                           \
            int p = idx >> 5, c = idx & 31;                                   \
            if (c < 16) R[it] = nbr[base_*MNBR + p];                          \
        } }

#define GATHER(GRP, R)                                                        \
    {   const int base_ = (GRP)*4;                                            \
        _Pragma("unroll")                                                     \
        for (int it = 0; it < 6; ++it) {                                      \
            int idx = it*256 + tid;                                           \
            int p = idx >> 5, c = idx & 31;                                   \
            if (c < 16) {                                                     \
                st[it] = *(const uint2*)(atomBf + ((size_t)R[it] << 6) + 4*c);\
            } else if (c < 27) {                                              \
                int cc = c - 16;                                              \
                int pa = p/12;                                                \
                const float* bp = bond + (size_t)(base_ + pa)*(MNBR*BDIM)     \
                                       + (p - pa*12)*BDIM + 4*cc;             \
                float b0 = bp[0], b1 = 0.f, b2 = 0.f, b3 = 0.f;               \
                if (cc < 10) { b1 = bp[1]; b2 = bp[2]; b3 = bp[3]; }          \
                st[it].x = pkbf(b0, b1); st[it].y = pkbf(b2, b3);             \
            }                                                                 \
        } }

#define WRITEA(BUF)                                                           \
    {   _Pragma("unroll")                                                     \
        for (int it = 0; it < 6; ++it) {                                      \
            int idx = it*256 + tid;                                           \
            int p = idx >> 5, c = idx & 31;                                   \
            if (c < 16)      *(uint2*)(&A[BUF][p*AR + 4*c]) = st[it];         \
            else if (c < 27) *(uint2*)(&A[BUF][p*AR + 64 + 4*(c-16)]) = st[it]; \
        } }

    const int S = gridDim.x;
    int grp = blockIdx.x;
    int cur = 0;
    if (grp < GROUPS) {
        LOAD_NBR(grp, rN);                        // indices for grp
        GATHER(grp, rN);                          // stage grp
        WRITEA(0);
        if (grp + S < GROUPS) LOAD_NBR(grp + S, rN);  // rN -> indices for grp+S
    }
    for (; grp < GROUPS; grp += S) {
        const int nxt = grp + S;
        __syncthreads();                          // A[cur] ready; prior reads done
        if (nxt < GROUPS) GATHER(nxt, rN);        // zero-wait: rN already resident
        if (nxt + S < GROUPS) LOAD_NBR(nxt + S, rM);  // indices for t+2
        f32x4 z = {0.f, 0.f, 0.f, 0.f};
        f32x4 acc[3][2];
        #pragma unroll
        for (int m = 0; m < 3; ++m) { acc[m][0] = z; acc[m][1] = z; }
        #pragma unroll
        for (int ks = 0; ks < 4; ++ks) {
            #pragma unroll
            for (int m = 0; m < 3; ++m) {
                short8 a = *(const short8*)(&A[cur][(m*16 + x)*AR + ks*32 + g*8]);
                acc[m][0] = __builtin_amdgcn_mfma_f32_16x16x32_bf16(a, B0[ks], acc[m][0], 0, 0, 0);
                acc[m][1] = __builtin_amdgcn_mfma_f32_16x16x32_bf16(a, B1[ks], acc[m][1], 0, 0, 0);
            }
        }
        const int base = grp*4;
        uint4* gbase = gated + ((size_t)grp*4 + w)*3*64 + lane;
        #pragma unroll
        for (int m = 0; m < 3; ++m) {
            int ia = base + (m*16 + g*4)/12;      // uniform over rg (proven)
            float ps0 = bf2f(PselfBf[(size_t)ia*C2F + ch0]);
            float ps1 = bf2f(PselfBf[(size_t)ia*C2F + 64 + ch0]);
            float v00 = acc[m][0][0] + ps0, v01 = acc[m][0][1] + ps0;
            float v02 = acc[m][0][2] + ps0, v03 = acc[m][0][3] + ps0;
            float v10 = acc[m][1][0] + ps1, v11 = acc[m][1][1] + ps1;
            float v12 = acc[m][1][2] + ps1, v13 = acc[m][1][3] + ps1;
            s0 += (v00 + v01) + (v02 + v03);
            s1 += (v10 + v11) + (v12 + v13);
            q0 = fmaf(v00, v00, q0); q0 = fmaf(v01, v01, q0);
            q0 = fmaf(v02, v02, q0); q0 = fmaf(v03, v03, q0);
            q1 = fmaf(v10, v10, q1); q1 = fmaf(v11, v11, q1);
            q1 = fmaf(v12, v12, q1); q1 = fmaf(v13, v13, q1);
            uint4 pk;
            pk.x = pkbf(v00, v01); pk.y = pkbf(v02, v03);
            pk.z = pkbf(v10, v11); pk.w = pkbf(v12, v13);
            gbase[m*64] = pk;
        }
        if (nxt < GROUPS) WRITEA(cur ^ 1);        // st arrived under MFMA+epilogue
        #pragma unroll
        for (int it = 0; it < 6; ++it) rN[it] = rM[it];
        cur ^= 1;
    }
#undef LOAD_NBR
#undef GATHER
#undef WRITEA
    s0 += __shfl_xor(s0, 16); s0 += __shfl_xor(s0, 32);
    s1 += __shfl_xor(s1, 16); s1 += __shfl_xor(s1, 32);
    q0 += __shfl_xor(q0, 16); q0 += __shfl_xor(q0, 32);
    q1 += __shfl_xor(q1, 16); q1 += __shfl_xor(q1, 32);
    if (g == 0) {
        float* pb = partial1 + blockIdx.x*256;     // {sum[128], sumsq[128]}
        pb[ch0]            = s0; pb[64 + ch0]        = s1;
        pb[C2F + ch0]      = q0; pb[C2F + 64 + ch0]  = q1;
    }
}

// ---------------- kernel: partial reduce 2048 -> 128 slots ----------------
__global__ __launch_bounds__(256) void k_red(
    const float* __restrict__ in, float* __restrict__ outp, int width)
{
    const int b = blockIdx.x;
    for (int c = threadIdx.x; c < width; c += 256) {
        float s = 0.f;
        #pragma unroll 4
        for (int k = 0; k < 16; ++k) s += in[(size_t)(b*16 + k)*width + c];
        outp[(size_t)b*width + c] = s;
    }
}

// ---------------- kernel 3: finalize BN1 params ----------------
__global__ __launch_bounds__(1024) void k_bn1_finalize(
    const float* __restrict__ red1, const float* __restrict__ scale,
    const float* __restrict__ offset, float* __restrict__ prm1)
{
    __shared__ float redS[1024], redQ[1024];
    const int tid = threadIdx.x, c = tid & 127, h = tid >> 7;   // 8 slices
    float S = 0.f, Q = 0.f;
    for (int blk = h; blk < 128; blk += 8) {
        S += red1[blk*256 + c];
        Q += red1[blk*256 + 128 + c];
    }
    redS[tid] = S; redQ[tid] = Q;
    __syncthreads();
    if (tid < 128) {
        float Sa = 0.f, Qa = 0.f;
        #pragma unroll
        for (int hh = 0; hh < 8; ++hh) { Sa += redS[hh*128 + c]; Qa += redQ[hh*128 + c]; }
        const float invn = 1.f / (float)(NATOMS * MNBR);
        float mean = Sa * invn;
        float var  = Qa * invn - mean*mean;
        float inv  = scale[c] * rsqrtf(var + EPSBN);
        prm1[c]       = inv;
        prm1[128 + c] = offset[c] - mean*inv;       // folded offset
    }
}

// ---------------- kernel 4: apply pass (stream gated, gate, nbr-sum) ----------------
__global__ __launch_bounds__(256, 8) void k_apply(
    const uint4* __restrict__ gated, const float* __restrict__ prm1,
    float* __restrict__ summed, float* __restrict__ partial2)
{
    __shared__ float Y[12*66];
    __shared__ float red[256];
    const int tid = threadIdx.x, w = tid >> 6, lane = tid & 63;
    const int g = lane >> 4, x = lane & 15;
    const int ch0 = w*16 + x;
    const float iv0 = prm1[ch0],      of0 = prm1[C2F + ch0];
    const float iv1 = prm1[64 + ch0], of1 = prm1[C2F + 64 + ch0];
    float s2 = 0.f, q2 = 0.f;

    for (int grp = blockIdx.x; grp < GROUPS; grp += gridDim.x) {
        __syncthreads();
        const uint4* gbase = gated + ((size_t)grp*4 + w)*3*64 + lane;
        #pragma unroll
        for (int m = 0; m < 3; ++m) {
            uint4 pk = gbase[m*64];
            float y00 = bflo(pk.x)*iv0 + of0, y01 = bfhi(pk.x)*iv0 + of0;
            float y02 = bflo(pk.y)*iv0 + of0, y03 = bfhi(pk.y)*iv0 + of0;
            float y10 = bflo(pk.z)*iv1 + of1, y11 = bfhi(pk.z)*iv1 + of1;
            float y12 = bflo(pk.w)*iv1 + of1, y13 = bfhi(pk.w)*iv1 + of1;
            float sY = sigmoidf(y00)*softplusf(y10) + sigmoidf(y01)*softplusf(y11)
                     + sigmoidf(y02)*softplusf(y12) + sigmoidf(y03)*softplusf(y13);
            Y[(m*4 + g)*66 + ch0] = sY;
        }
        __syncthreads();
        float sv = Y[(3*w)*66 + lane] + Y[(3*w + 1)*66 + lane] + Y[(3*w + 2)*66 + lane];
        summed[(size_t)(grp*4 + w)*FDIM + lane] = sv;
        s2 += sv; q2 = fmaf(sv, sv, q2);
    }
    red[tid] = s2; __syncthreads();
    if (tid < 64) partial2[blockIdx.x*128 + tid]
        = red[tid] + red[tid+64] + red[tid+128] + red[tid+192];
    __syncthreads();
    red[tid] = q2; __syncthreads();
    if (tid < 64) partial2[blockIdx.x*128 + 64 + tid]
        = red[tid] + red[tid+64] + red[tid+128] + red[tid+192];
}

// ---------------- kernel 5: finalize BN2 params ----------------
__global__ __launch_bounds__(1024) void k_bn2_finalize(
    const float* __restrict__ red2, const float* __restrict__ scale,
    const float* __restrict__ offset, float* __restrict__ prm2)
{
    __shared__ float redS[1024], redQ[1024];
    const int tid = threadIdx.x, f = tid & 63, h = tid >> 6;    // 16 slices
    float S = 0.f, Q = 0.f;
    for (int blk = h; blk < 128; blk += 16) {
        S += red2[blk*128 + f];
        Q += red2[blk*128 + 64 + f];
    }
    redS[tid] = S; redQ[tid] = Q;
    __syncthreads();
    if (tid < 64) {
        float Sa = 0.f, Qa = 0.f;
        #pragma unroll
        for (int hh = 0; hh < 16; ++hh) { Sa += redS[hh*64 + f]; Qa += redQ[hh*64 + f]; }
        const float invn = 1.f / (float)NATOMS;
        float mean = Sa * invn;
        float var  = Qa * invn - mean*mean;
        float inv  = scale[f] * rsqrtf(var + EPSBN);
        prm2[f]      = inv;
        prm2[64 + f] = offset[f] - mean*inv;
    }
}

// ---------------- kernel 6: residual + softplus ----------------
__global__ __launch_bounds__(256) void k_final(
    const float* __restrict__ atomF, const float* __restrict__ summed,
    const float* __restrict__ prm2, float* __restrict__ out)
{
    __shared__ float iv[64], of[64];
    if (threadIdx.x < 64) {
        iv[threadIdx.x] = prm2[threadIdx.x];
        of[threadIdx.x] = prm2[64 + threadIdx.x];
    }
    __syncthreads();
    const int total4 = NATOMS*FDIM/4;
    for (int t = blockIdx.x*blockDim.x + threadIdx.x; t < total4;
         t += gridDim.x*blockDim.x) {
        float4 a = ((const float4*)atomF)[t];
        float4 s = ((const float4*)summed)[t];
        int fb = (t*4) & 63;
        float4 r;
        r.x = softplusf(a.x + s.x*iv[fb]   + of[fb]);
        r.y = softplusf(a.y + s.y*iv[fb+1] + of[fb+1]);
        r.z = softplusf(a.z + s.z*iv[fb+2] + of[fb+2]);
        r.w = softplusf(a.w + s.w*iv[fb+3] + of[fb+3]);
        ((float4*)out)[t] = r;
    }
}

extern "C" void kernel_launch(void* const* d_in, const int* in_sizes, int n_in,
                              void* d_out, int out_size, void* d_ws, size_t ws_size,
                              hipStream_t stream)
{
    const int*   nbr   = (const int*)  d_in[0];
    const float* atomF = (const float*)d_in[1];
    const float* bond  = (const float*)d_in[2];
    const float* W     = (const float*)d_in[3];
    // d_in[4] = b: cancels through BN1 (shift invariance) -> unused
    const float* s1    = (const float*)d_in[5];
    const float* o1    = (const float*)d_in[6];
    const float* s2    = (const float*)d_in[7];
    const float* o2    = (const float*)d_in[8];
    float* out = (float*)d_out;

    // ws layout (~375 MB total)
    uint4* gated        = (uint4*)d_ws;                          // GROUPS*12*64*16B = 307.2MB
    unsigned short* PselfBf = (unsigned short*)(gated + (size_t)GROUPS*12*64);  // N*128 bf16
    unsigned short* atomBf  = PselfBf + (size_t)NATOMS*C2F;      // N*64 bf16
    float* summed   = (float*)(atomBf + (size_t)NATOMS*FDIM);    // N*64 f32
    float* partial1 = summed   + (size_t)NATOMS*FDIM;            // 2048*256
    float* partial2 = partial1 + (size_t)NBLK*256;               // 2048*128
    float* red1     = partial2 + (size_t)NBLK*128;               // 128*256
    float* red2     = red1     + 128*256;                        // 128*128
    float* prm1     = red2     + 128*128;                        // 256
    float* prm2     = prm1     + 256;                            // 128
    unsigned short* Wsn = (unsigned short*)(prm2 + 128);         // 8192 shorts
    unsigned short* Wpk = Wsn + 8192;                            // 16384 shorts

    hipLaunchKernelGGL(k_pack,         dim3(64),   dim3(256),  0, stream, W, Wsn, Wpk);
    hipLaunchKernelGGL(k_proj,         dim3(782),  dim3(256),  0, stream,
                       atomF, Wsn, PselfBf, atomBf);
    hipLaunchKernelGGL(k_gemm,         dim3(NBLK), dim3(256),  0, stream,
                       nbr, atomBf, bond, Wpk, PselfBf, gated, partial1);
    hipLaunchKernelGGL(k_red,          dim3(128),  dim3(256),  0, stream, partial1, red1, 256);
    hipLaunchKernelGGL(k_bn1_finalize, dim3(1),    dim3(1024), 0, stream, red1, s1, o1, prm1);
    hipLaunchKernelGGL(k_apply,        dim3(NBLK), dim3(256),  0, stream,
                       gated, prm1, summed, partial2);
    hipLaunchKernelGGL(k_red,          dim3(128),  dim3(256),  0, stream, partial2, red2, 128);
    hipLaunchKernelGGL(k_bn2_finalize, dim3(1),    dim3(1024), 0, stream, red2, s2, o2, prm2);
    hipLaunchKernelGGL(k_final,        dim3(2048), dim3(256),  0, stream, atomF, summed, prm2, out);
}